// Round 1
// baseline (393.832 us; speedup 1.0000x reference)
//
#include <hip/hip_runtime.h>
#include <hip/hip_bf16.h>

#define C_DIM 64
#define M_DIM 8
#define O_DIM 64

typedef __bf16 bf16x8 __attribute__((ext_vector_type(8)));
typedef float f32x4 __attribute__((ext_vector_type(4)));

// xu[v][m] = sum_c data[v][c] * u[c][m]
__global__ void xu_kernel(const float* __restrict__ data, const float* __restrict__ u,
                          float* __restrict__ xu, int V) {
    int t = blockIdx.x * blockDim.x + threadIdx.x;
    if (t >= V * M_DIM) return;
    int v = t >> 3, m = t & 7;
    const float* dr = data + (size_t)v * C_DIM;
    float s = 0.f;
#pragma unroll
    for (int c = 0; c < C_DIM; ++c) s = fmaf(dr[c], u[c * M_DIM + m], s);
    xu[t] = s;
}

// Repack var_w [M,C,O] (k = m*64+c rows, o cols) into MFMA B-fragment order:
// bfrag[((kt*4+nt)*64 + lane)*8 + j] = bf16( Wflat[kt*32 + (lane>>4)*8 + j][nt*16 + (lane&15)] )
__global__ void wb_kernel(const float* __restrict__ w, __bf16* __restrict__ bfrag) {
    int t = blockIdx.x * blockDim.x + threadIdx.x;
    if (t >= 16 * 4 * 64) return;
    int kt = t >> 8;
    int rem = t & 255;
    int nt = rem >> 6;
    int lane = rem & 63;
    int quad = lane >> 4;
    int n = nt * 16 + (lane & 15);
#pragma unroll
    for (int j = 0; j < 8; ++j) {
        int k = kt * 32 + quad * 8 + j;
        bfrag[(size_t)t * 8 + j] = (__bf16)w[k * 64 + n];
    }
}

__global__ void hist_kernel(const int* __restrict__ src, int* __restrict__ counts, int E) {
    int e = blockIdx.x * blockDim.x + threadIdx.x;
    if (e < E) atomicAdd(&counts[src[e]], 1);
}

// 3-phase exclusive scan over counts[V] -> offsets[V]
__global__ void scan_a(const int* __restrict__ counts, int* __restrict__ incl,
                       int* __restrict__ bsums, int V) {
    __shared__ int s[1024];
    int g = blockIdx.x * 1024 + threadIdx.x;
    int x = (g < V) ? counts[g] : 0;
    s[threadIdx.x] = x;
    __syncthreads();
    for (int off = 1; off < 1024; off <<= 1) {
        int add = (threadIdx.x >= off) ? s[threadIdx.x - off] : 0;
        __syncthreads();
        s[threadIdx.x] += add;
        __syncthreads();
    }
    if (g < V) incl[g] = s[threadIdx.x];
    if (threadIdx.x == 1023) bsums[blockIdx.x] = s[1023];
}

__global__ void scan_b(int* __restrict__ bsums, int nb) {
    if (blockIdx.x == 0 && threadIdx.x == 0) {
        int r = 0;
        for (int i = 0; i < nb; ++i) { r += bsums[i]; bsums[i] = r; }
    }
}

__global__ void scan_c(const int* __restrict__ counts, const int* __restrict__ incl,
                       const int* __restrict__ bsums, int* __restrict__ offsets, int V) {
    int g = blockIdx.x * 1024 + threadIdx.x;
    if (g >= V) return;
    int base = (blockIdx.x > 0) ? bsums[blockIdx.x - 1] : 0;
    offsets[g] = base + incl[g] - counts[g];
}

// Per edge: compute softmax gate * weight, scatter into CSR slot.
__global__ void scatter_kernel(const int* __restrict__ src, const int* __restrict__ dst,
                               const float* __restrict__ wt, const float* __restrict__ xu,
                               const float* __restrict__ vc, const int* __restrict__ offsets,
                               int* __restrict__ cursor, int* __restrict__ es_dst,
                               float* __restrict__ qw, int E) {
    int e = blockIdx.x * blockDim.x + threadIdx.x;
    if (e >= E) return;
    int s = src[e], j = dst[e];
    float w = wt[e];
    float lg[8];
    float mx = -1e30f;
#pragma unroll
    for (int m = 0; m < 8; ++m) {
        lg[m] = xu[s * 8 + m] - xu[j * 8 + m] + vc[m];
        mx = fmaxf(mx, lg[m]);
    }
    float den = 0.f;
#pragma unroll
    for (int m = 0; m < 8; ++m) {
        lg[m] = __expf(lg[m] - mx);
        den += lg[m];
    }
    float inv = w / den;
    int pos = offsets[s] + atomicAdd(&cursor[s], 1);
    es_dst[pos] = j;
#pragma unroll
    for (int m = 0; m < 8; ++m) qw[(size_t)pos * 8 + m] = lg[m] * inv;
}

// Fused: per 16-vertex tile, CSR edge accumulation into LDS bf16 A-tile,
// then 16x16x32 bf16 MFMA against pre-packed W fragments, + bias, store.
#define A_STRIDE 520  // ushorts per row: 16B-aligned rows, 2-way bank aliasing only (free)
__global__ __launch_bounds__(256) void fused_kernel(
    const float* __restrict__ data, const int* __restrict__ es_dst,
    const float* __restrict__ qw, const int* __restrict__ counts,
    const int* __restrict__ offsets, const __bf16* __restrict__ bfragG,
    const float* __restrict__ bias, float* __restrict__ out, int V) {
    __shared__ __bf16 At[16 * A_STRIDE];
    int wave = threadIdx.x >> 6;
    int lane = threadIdx.x & 63;
    int v_base = blockIdx.x * 16;

    // Edge accumulation: wave handles rows wave*4 .. wave*4+3 (one vertex each, sequential)
    for (int i = 0; i < 4; ++i) {
        int row = wave * 4 + i;
        int v = v_base + row;
        float acc[8] = {0.f, 0.f, 0.f, 0.f, 0.f, 0.f, 0.f, 0.f};
        if (v < V) {
            int deg = counts[v];
            int off = offsets[v];
            for (int t = 0; t < deg; ++t) {
                int e = off + t;
                int j = es_dst[e];
                float x = data[(size_t)j * 64 + lane];
#pragma unroll
                for (int m = 0; m < 8; ++m) acc[m] = fmaf(qw[(size_t)e * 8 + m], x, acc[m]);
            }
        }
#pragma unroll
        for (int m = 0; m < 8; ++m) At[row * A_STRIDE + m * 64 + lane] = (__bf16)acc[m];
    }
    __syncthreads();

    // MFMA phase: wave = nt (output column tile), D[16 rows x 16 cols]
    f32x4 cacc = {0.f, 0.f, 0.f, 0.f};
    int quad = lane >> 4;
    int r16 = lane & 15;
#pragma unroll
    for (int kt = 0; kt < 16; ++kt) {
        bf16x8 a = *(const bf16x8*)&At[r16 * A_STRIDE + kt * 32 + quad * 8];
        bf16x8 b = *(const bf16x8*)&bfragG[((size_t)(kt * 4 + wave) * 64 + lane) * 8];
        cacc = __builtin_amdgcn_mfma_f32_16x16x32_bf16(a, b, cacc, 0, 0, 0);
    }
#pragma unroll
    for (int r = 0; r < 4; ++r) {
        int row = quad * 4 + r;
        int v = v_base + row;
        if (v < V) {
            int o = wave * 16 + r16;
            out[(size_t)v * 64 + o] = cacc[r] + bias[o];
        }
    }
}

extern "C" void kernel_launch(void* const* d_in, const int* in_sizes, int n_in,
                              void* d_out, int out_size, void* d_ws, size_t ws_size,
                              hipStream_t stream) {
    const float* data  = (const float*)d_in[0];
    const int*   esrc  = (const int*)d_in[1];
    const int*   edst  = (const int*)d_in[2];
    const float* ew    = (const float*)d_in[3];
    const float* var_u = (const float*)d_in[4];
    const float* var_c = (const float*)d_in[5];
    const float* var_w = (const float*)d_in[6];
    const float* var_b = (const float*)d_in[7];
    float* out = (float*)d_out;

    int V = in_sizes[0] / C_DIM;
    int E = in_sizes[1];

    char* ws = (char*)d_ws;
    size_t off = 0;
    auto alloc = [&](size_t bytes) -> void* {
        void* p = ws + off;
        off = (off + bytes + 255) & ~(size_t)255;
        return p;
    };
    float*  xu      = (float*)alloc((size_t)V * 8 * 4);
    int*    counts  = (int*)alloc((size_t)V * 4);
    int*    offsets = (int*)alloc((size_t)V * 4);
    int*    cursor  = (int*)alloc((size_t)V * 4);
    int*    incl    = (int*)alloc((size_t)V * 4);
    int*    bsums   = (int*)alloc(4096);
    int*    es_dst  = (int*)alloc((size_t)E * 4);
    float*  qw      = (float*)alloc((size_t)E * 8 * 4);
    __bf16* bfrag   = (__bf16*)alloc((size_t)512 * 64 * 2);

    hipMemsetAsync(counts, 0, (size_t)V * 4, stream);
    hipMemsetAsync(cursor, 0, (size_t)V * 4, stream);

    xu_kernel<<<(V * M_DIM + 255) / 256, 256, 0, stream>>>(data, var_u, xu, V);
    wb_kernel<<<16, 256, 0, stream>>>(var_w, bfrag);
    hist_kernel<<<(E + 255) / 256, 256, 0, stream>>>(esrc, counts, E);

    int nb = (V + 1023) / 1024;
    scan_a<<<nb, 1024, 0, stream>>>(counts, incl, bsums, V);
    scan_b<<<1, 64, 0, stream>>>(bsums, nb);
    scan_c<<<nb, 1024, 0, stream>>>(counts, incl, bsums, offsets, V);

    scatter_kernel<<<(E + 255) / 256, 256, 0, stream>>>(esrc, edst, ew, xu, var_c,
                                                        offsets, cursor, es_dst, qw, E);
    fused_kernel<<<(V + 15) / 16, 256, 0, stream>>>(data, es_dst, qw, counts, offsets,
                                                    bfrag, var_b, out, V);
}

// Round 2
// 333.620 us; speedup vs baseline: 1.1805x; 1.1805x over previous
//
#include <hip/hip_runtime.h>
#include <hip/hip_bf16.h>

#define C_DIM 64
#define M_DIM 8
#define O_DIM 64

typedef __bf16 bf16x8 __attribute__((ext_vector_type(8)));
typedef float f32x4 __attribute__((ext_vector_type(4)));

__device__ __forceinline__ float bf2f(unsigned short u) {
    return __uint_as_float(((unsigned int)u) << 16);
}

// xu[v][m] = sum_c data[v][c] * u[c][m]
__global__ void xu_kernel(const float* __restrict__ data, const float* __restrict__ u,
                          float* __restrict__ xu, int V) {
    int t = blockIdx.x * blockDim.x + threadIdx.x;
    if (t >= V * M_DIM) return;
    int v = t >> 3, m = t & 7;
    const float* dr = data + (size_t)v * C_DIM;
    float s = 0.f;
#pragma unroll
    for (int c = 0; c < C_DIM; ++c) s = fmaf(dr[c], u[c * M_DIM + m], s);
    xu[t] = s;
}

// data (fp32) -> bf16 copy, RNE. One thread per 4 elements.
__global__ void databf_kernel(const float* __restrict__ data,
                              unsigned short* __restrict__ db, int n4) {
    int t = blockIdx.x * blockDim.x + threadIdx.x;
    if (t >= n4) return;
    f32x4 x = *(const f32x4*)&data[(size_t)t * 4];
    ushort4 o;
    o.x = __bfloat16_as_ushort(__float2bfloat16(x[0]));
    o.y = __bfloat16_as_ushort(__float2bfloat16(x[1]));
    o.z = __bfloat16_as_ushort(__float2bfloat16(x[2]));
    o.w = __bfloat16_as_ushort(__float2bfloat16(x[3]));
    *(ushort4*)&db[(size_t)t * 4] = o;
}

// Repack var_w [M,C,O] into MFMA B-fragment order (see R0 comment)
__global__ void wb_kernel(const float* __restrict__ w, __bf16* __restrict__ bfrag) {
    int t = blockIdx.x * blockDim.x + threadIdx.x;
    if (t >= 16 * 4 * 64) return;
    int kt = t >> 8;
    int rem = t & 255;
    int nt = rem >> 6;
    int lane = rem & 63;
    int quad = lane >> 4;
    int n = nt * 16 + (lane & 15);
#pragma unroll
    for (int j = 0; j < 8; ++j) {
        int k = kt * 32 + quad * 8 + j;
        bfrag[(size_t)t * 8 + j] = (__bf16)w[k * 64 + n];
    }
}

__global__ void hist_kernel(const int* __restrict__ src, int* __restrict__ counts, int E) {
    int e = blockIdx.x * blockDim.x + threadIdx.x;
    if (e < E) atomicAdd(&counts[src[e]], 1);
}

// 3-phase exclusive scan over counts[V] -> offsets[V]
__global__ void scan_a(const int* __restrict__ counts, int* __restrict__ incl,
                       int* __restrict__ bsums, int V) {
    __shared__ int s[1024];
    int g = blockIdx.x * 1024 + threadIdx.x;
    int x = (g < V) ? counts[g] : 0;
    s[threadIdx.x] = x;
    __syncthreads();
    for (int off = 1; off < 1024; off <<= 1) {
        int add = (threadIdx.x >= off) ? s[threadIdx.x - off] : 0;
        __syncthreads();
        s[threadIdx.x] += add;
        __syncthreads();
    }
    if (g < V) incl[g] = s[threadIdx.x];
    if (threadIdx.x == 1023) bsums[blockIdx.x] = s[1023];
}

__global__ void scan_b(int* __restrict__ bsums, int nb) {
    if (blockIdx.x == 0 && threadIdx.x == 0) {
        int r = 0;
        for (int i = 0; i < nb; ++i) { r += bsums[i]; bsums[i] = r; }
    }
}

__global__ void scan_c(const int* __restrict__ counts, const int* __restrict__ incl,
                       const int* __restrict__ bsums, int* __restrict__ offsets, int V) {
    int g = blockIdx.x * 1024 + threadIdx.x;
    if (g >= V) return;
    int base = (blockIdx.x > 0) ? bsums[blockIdx.x - 1] : 0;
    offsets[g] = base + incl[g] - counts[g];
}

// Per edge: softmax gate * weight, scatter into CSR slot.
__global__ void scatter_kernel(const int* __restrict__ src, const int* __restrict__ dst,
                               const float* __restrict__ wt, const float* __restrict__ xu,
                               const float* __restrict__ vc, const int* __restrict__ offsets,
                               int* __restrict__ cursor, int* __restrict__ es_dst,
                               float* __restrict__ qw, int E) {
    int e = blockIdx.x * blockDim.x + threadIdx.x;
    if (e >= E) return;
    int s = src[e], j = dst[e];
    float w = wt[e];
    float lg[8];
    float mx = -1e30f;
#pragma unroll
    for (int m = 0; m < 8; ++m) {
        lg[m] = xu[s * 8 + m] - xu[j * 8 + m] + vc[m];
        mx = fmaxf(mx, lg[m]);
    }
    float den = 0.f;
#pragma unroll
    for (int m = 0; m < 8; ++m) {
        lg[m] = __expf(lg[m] - mx);
        den += lg[m];
    }
    float inv = w / den;
    int pos = offsets[s] + atomicAdd(&cursor[s], 1);
    es_dst[pos] = j;
#pragma unroll
    for (int m = 0; m < 8; ++m) qw[(size_t)pos * 8 + m] = lg[m] * inv;
}

// Fused: per 16-vertex tile, CSR edge accumulation (bf16 gather, 8-deep MLP)
// into LDS bf16 A-tile, then 16x16x32 bf16 MFMA, + bias, store.
#define A_STRIDE 520
__global__ __launch_bounds__(256) void fused_kernel(
    const unsigned short* __restrict__ databf, const int* __restrict__ es_dst,
    const float* __restrict__ qw, const int* __restrict__ counts,
    const int* __restrict__ offsets, const __bf16* __restrict__ bfragG,
    const float* __restrict__ bias, float* __restrict__ out, int V) {
    __shared__ __bf16 At[16 * A_STRIDE];
    int wave = __builtin_amdgcn_readfirstlane(threadIdx.x >> 6);
    int lane = threadIdx.x & 63;
    int v_base = blockIdx.x * 16;

    for (int i = 0; i < 4; ++i) {
        int row = wave * 4 + i;
        int v = v_base + row;
        float acc[8] = {0.f, 0.f, 0.f, 0.f, 0.f, 0.f, 0.f, 0.f};
        if (v < V) {
            int deg = __builtin_amdgcn_readfirstlane(counts[v]);
            int off = __builtin_amdgcn_readfirstlane(offsets[v]);
            int t = 0;
            // 8-deep unroll: 8 independent gathers in flight
            for (; t + 8 <= deg; t += 8) {
                int e = off + t;
                int j[8];
#pragma unroll
                for (int u = 0; u < 8; ++u)
                    j[u] = __builtin_amdgcn_readfirstlane(es_dst[e + u]);
                float x[8];
#pragma unroll
                for (int u = 0; u < 8; ++u)
                    x[u] = bf2f(databf[(size_t)j[u] * 64 + lane]);
#pragma unroll
                for (int u = 0; u < 8; ++u) {
#pragma unroll
                    for (int m = 0; m < 8; ++m)
                        acc[m] = fmaf(qw[(size_t)(e + u) * 8 + m], x[u], acc[m]);
                }
            }
            for (; t + 4 <= deg; t += 4) {
                int e = off + t;
                int j[4];
#pragma unroll
                for (int u = 0; u < 4; ++u)
                    j[u] = __builtin_amdgcn_readfirstlane(es_dst[e + u]);
                float x[4];
#pragma unroll
                for (int u = 0; u < 4; ++u)
                    x[u] = bf2f(databf[(size_t)j[u] * 64 + lane]);
#pragma unroll
                for (int u = 0; u < 4; ++u) {
#pragma unroll
                    for (int m = 0; m < 8; ++m)
                        acc[m] = fmaf(qw[(size_t)(e + u) * 8 + m], x[u], acc[m]);
                }
            }
            for (; t < deg; ++t) {
                int e = off + t;
                int j0 = __builtin_amdgcn_readfirstlane(es_dst[e]);
                float x0 = bf2f(databf[(size_t)j0 * 64 + lane]);
#pragma unroll
                for (int m = 0; m < 8; ++m)
                    acc[m] = fmaf(qw[(size_t)e * 8 + m], x0, acc[m]);
            }
        }
#pragma unroll
        for (int m = 0; m < 8; ++m) At[row * A_STRIDE + m * 64 + lane] = (__bf16)acc[m];
    }
    __syncthreads();

    // MFMA phase: wave = output column tile
    f32x4 cacc = {0.f, 0.f, 0.f, 0.f};
    int quad = lane >> 4;
    int r16 = lane & 15;
#pragma unroll
    for (int kt = 0; kt < 16; ++kt) {
        bf16x8 a = *(const bf16x8*)&At[r16 * A_STRIDE + kt * 32 + quad * 8];
        bf16x8 b = *(const bf16x8*)&bfragG[((size_t)(kt * 4 + wave) * 64 + lane) * 8];
        cacc = __builtin_amdgcn_mfma_f32_16x16x32_bf16(a, b, cacc, 0, 0, 0);
    }
#pragma unroll
    for (int r = 0; r < 4; ++r) {
        int row = quad * 4 + r;
        int v = v_base + row;
        if (v < V) {
            int o = wave * 16 + r16;
            out[(size_t)v * 64 + o] = cacc[r] + bias[o];
        }
    }
}

extern "C" void kernel_launch(void* const* d_in, const int* in_sizes, int n_in,
                              void* d_out, int out_size, void* d_ws, size_t ws_size,
                              hipStream_t stream) {
    const float* data  = (const float*)d_in[0];
    const int*   esrc  = (const int*)d_in[1];
    const int*   edst  = (const int*)d_in[2];
    const float* ew    = (const float*)d_in[3];
    const float* var_u = (const float*)d_in[4];
    const float* var_c = (const float*)d_in[5];
    const float* var_w = (const float*)d_in[6];
    const float* var_b = (const float*)d_in[7];
    float* out = (float*)d_out;

    int V = in_sizes[0] / C_DIM;
    int E = in_sizes[1];

    char* ws = (char*)d_ws;
    size_t off = 0;
    auto alloc = [&](size_t bytes) -> void* {
        void* p = ws + off;
        off = (off + bytes + 255) & ~(size_t)255;
        return p;
    };
    float*  xu      = (float*)alloc((size_t)V * 8 * 4);
    int*    counts  = (int*)alloc((size_t)V * 4);
    int*    offsets = (int*)alloc((size_t)V * 4);
    int*    cursor  = (int*)alloc((size_t)V * 4);
    int*    incl    = (int*)alloc((size_t)V * 4);
    int*    bsums   = (int*)alloc(4096);
    int*    es_dst  = (int*)alloc((size_t)E * 4);
    float*  qw      = (float*)alloc((size_t)E * 8 * 4);
    __bf16* bfrag   = (__bf16*)alloc((size_t)512 * 64 * 2);
    unsigned short* databf = (unsigned short*)alloc((size_t)V * 64 * 2);

    hipMemsetAsync(counts, 0, (size_t)V * 4, stream);
    hipMemsetAsync(cursor, 0, (size_t)V * 4, stream);

    xu_kernel<<<(V * M_DIM + 255) / 256, 256, 0, stream>>>(data, var_u, xu, V);
    databf_kernel<<<(V * 16 + 255) / 256, 256, 0, stream>>>(data, databf, V * 16);
    wb_kernel<<<16, 256, 0, stream>>>(var_w, bfrag);
    hist_kernel<<<(E + 255) / 256, 256, 0, stream>>>(esrc, counts, E);

    int nb = (V + 1023) / 1024;
    scan_a<<<nb, 1024, 0, stream>>>(counts, incl, bsums, V);
    scan_b<<<1, 64, 0, stream>>>(bsums, nb);
    scan_c<<<nb, 1024, 0, stream>>>(counts, incl, bsums, offsets, V);

    scatter_kernel<<<(E + 255) / 256, 256, 0, stream>>>(esrc, edst, ew, xu, var_c,
                                                        offsets, cursor, es_dst, qw, E);
    fused_kernel<<<(V + 15) / 16, 256, 0, stream>>>(databf, es_dst, qw, counts, offsets,
                                                    bfrag, var_b, out, V);
}